// Round 1
// baseline (468.056 us; speedup 1.0000x reference)
//
#include <hip/hip_runtime.h>
#include <hip/hip_bf16.h>

// Problem constants
#define B_DIM   512
#define IN_DIM  4096
#define OUT_DIM 11008

typedef __bf16 bf16x4 __attribute__((ext_vector_type(4)));
typedef __bf16 bf16x8 __attribute__((ext_vector_type(8)));
typedef float  floatx4 __attribute__((ext_vector_type(4)));

// ---------------------------------------------------------------------------
// Pass 1: decode QINS weights (int32 stored in [1,255], int32 sign ±1) -> bf16
// w = sign * exp(lmin + (255 - s)/254 * (lmax - lmin))
// 4 elements / thread, int4 loads, bf16x4 store. HBM-bound: 450 MB.
// ---------------------------------------------------------------------------
__global__ __launch_bounds__(256) void decode_w_kernel(
    const int* __restrict__ stored, const int* __restrict__ sign,
    const float* __restrict__ logmin, const float* __restrict__ logmax,
    __bf16* __restrict__ w) {
  int idx = blockIdx.x * blockDim.x + threadIdx.x;  // quad index
  float lmin  = logmin[0];
  float slope = (logmax[0] - lmin) * (1.0f / 254.0f);
  int4 s = ((const int4*)stored)[idx];
  int4 g = ((const int4*)sign)[idx];
  float w0 = __expf(lmin + (float)(255 - s.x) * slope) * (float)g.x;
  float w1 = __expf(lmin + (float)(255 - s.y) * slope) * (float)g.y;
  float w2 = __expf(lmin + (float)(255 - s.z) * slope) * (float)g.z;
  float w3 = __expf(lmin + (float)(255 - s.w) * slope) * (float)g.w;
  bf16x4 o;
  o[0] = (__bf16)w0; o[1] = (__bf16)w1; o[2] = (__bf16)w2; o[3] = (__bf16)w3;
  ((bf16x4*)w)[idx] = o;
}

// ---------------------------------------------------------------------------
// Pass 1b: x fp32 -> bf16
// ---------------------------------------------------------------------------
__global__ __launch_bounds__(256) void conv_x_kernel(
    const float* __restrict__ x, __bf16* __restrict__ xb) {
  int idx = blockIdx.x * blockDim.x + threadIdx.x;  // quad index
  float4 v = ((const float4*)x)[idx];
  bf16x4 o;
  o[0] = (__bf16)v.x; o[1] = (__bf16)v.y; o[2] = (__bf16)v.z; o[3] = (__bf16)v.w;
  ((bf16x4*)xb)[idx] = o;
}

// ---------------------------------------------------------------------------
// Pass 2: m97-structure bf16 GEMM, C = A(512x4096) * W^T(4096x11008)
// A row-major (M x K), W row-major (N x K)  -> "gemm_bt" layout.
// 128x128 tile, BK=32, 256 threads = 4 waves in 2x2; each wave 64x64 via
// 4x4 grid of mfma_f32_16x16x32_bf16. global_load_lds width=16 staging.
// Epilogue: out = acc*scale + bias*scale (fp32).
// ---------------------------------------------------------------------------
__device__ __forceinline__ void gl_lds16(const __bf16* g, __bf16* l) {
  __builtin_amdgcn_global_load_lds(
      (const __attribute__((address_space(1))) void*)g,
      (__attribute__((address_space(3))) void*)l, 16, 0, 0);
}

__global__ __launch_bounds__(256, 2) void gemm_bt_kernel(
    const __bf16* __restrict__ A,    // 512 x 4096 (x, bf16)
    const __bf16* __restrict__ Bw,   // 11008 x 4096 (W, bf16)
    const float* __restrict__ scale, const float* __restrict__ bias,
    float* __restrict__ out) {
  constexpr int K = IN_DIM, N = OUT_DIM;
  constexpr int BM = 128, BN = 128, BK = 32;

  __shared__ __align__(16) __bf16 sA[BM * BK];  // 8 KB, row-major, stride 32
  __shared__ __align__(16) __bf16 sB[BN * BK];  // 8 KB

  const int tid  = threadIdx.x;
  const int lane = tid & 63;
  const int wave = tid >> 6;
  const int wm   = (wave >> 1) * 64;   // wave row offset in tile
  const int wn   = (wave & 1) * 64;    // wave col offset in tile
  const int m16  = lane & 15;
  const int q    = lane >> 4;          // quad 0..3

  const int bn0 = blockIdx.x * BN;
  const int bm0 = blockIdx.y * BM;

  // Staging: 16 B per lane; 2 chunks per tile (256 thr * 16 B = 4 KB/chunk).
  // LDS layout = unpadded row-major (lane-ordered, global_load_lds caveat).
  const int r0 = tid >> 2;             // rows 0..63  (chunk 0)
  const int c0 = (tid & 3) * 8;        // bf16 col offset {0,8,16,24}
  const __bf16* gA0 = A  + (bm0 + r0) * K + c0;
  const __bf16* gA1 = A  + (bm0 + r0 + 64) * K + c0;
  const __bf16* gB0 = Bw + (bn0 + r0) * K + c0;
  const __bf16* gB1 = Bw + (bn0 + r0 + 64) * K + c0;
  __bf16* lA0 = sA + tid * 8;          // byte offset tid*16
  __bf16* lA1 = sA + 2048 + tid * 8;
  __bf16* lB0 = sB + tid * 8;
  __bf16* lB1 = sB + 2048 + tid * 8;

  floatx4 acc[4][4] = {};

  for (int kt = 0; kt < K; kt += BK) {
    __syncthreads();                   // protect LDS from overwrite
    gl_lds16(gA0 + kt, lA0);
    gl_lds16(gA1 + kt, lA1);
    gl_lds16(gB0 + kt, lB0);
    gl_lds16(gB1 + kt, lB1);
    __syncthreads();                   // compiler drains vmcnt before barrier

    bf16x8 afr[4], bfr[4];
#pragma unroll
    for (int i = 0; i < 4; ++i)
      afr[i] = *(const bf16x8*)&sA[(wm + i * 16 + m16) * BK + q * 8];
#pragma unroll
    for (int i = 0; i < 4; ++i)
      bfr[i] = *(const bf16x8*)&sB[(wn + i * 16 + m16) * BK + q * 8];

#pragma unroll
    for (int mi = 0; mi < 4; ++mi)
#pragma unroll
      for (int ni = 0; ni < 4; ++ni)
        acc[mi][ni] = __builtin_amdgcn_mfma_f32_16x16x32_bf16(
            afr[mi], bfr[ni], acc[mi][ni], 0, 0, 0);
  }

  // Epilogue. C/D layout: col = lane&15, row = q*4 + reg  [m89]
#pragma unroll
  for (int ni = 0; ni < 4; ++ni) {
    const int col = bn0 + wn + ni * 16 + m16;
    const float sc = scale[col];
    const float bb = bias[col] * sc;
#pragma unroll
    for (int mi = 0; mi < 4; ++mi) {
#pragma unroll
      for (int r = 0; r < 4; ++r) {
        const int row = bm0 + wm + mi * 16 + q * 4 + r;
        out[row * N + col] = acc[mi][ni][r] * sc + bb;
      }
    }
  }
}

// ---------------------------------------------------------------------------
extern "C" void kernel_launch(void* const* d_in, const int* in_sizes, int n_in,
                              void* d_out, int out_size, void* d_ws, size_t ws_size,
                              hipStream_t stream) {
  const float* x      = (const float*)d_in[0];
  const int*   stored = (const int*)d_in[1];
  const int*   sign   = (const int*)d_in[2];
  const float* logmin = (const float*)d_in[3];
  const float* logmax = (const float*)d_in[4];
  const float* scale  = (const float*)d_in[5];
  const float* bias   = (const float*)d_in[6];
  float* out = (float*)d_out;

  __bf16* wsW = (__bf16*)d_ws;                       // 11008*4096 bf16 = 90.2 MB
  __bf16* wsX = wsW + (size_t)OUT_DIM * IN_DIM;      // 512*4096 bf16 = 4 MB

  // decode W: 45,088,768 elems / 4 per thread / 256 per block = 44032 blocks
  decode_w_kernel<<<(OUT_DIM * (IN_DIM / 4)) / 256, 256, 0, stream>>>(
      stored, sign, logmin, logmax, wsW);
  // convert x: 2,097,152 elems / 4 / 256 = 2048 blocks
  conv_x_kernel<<<(B_DIM * (IN_DIM / 4)) / 256, 256, 0, stream>>>(x, wsX);
  // GEMM: grid (N/128, M/128) = (86, 4)
  gemm_bt_kernel<<<dim3(OUT_DIM / 128, B_DIM / 128), 256, 0, stream>>>(
      wsX, wsW, scale, bias, out);
}